// Round 7
// baseline (833.570 us; speedup 1.0000x reference)
//
#include <hip/hip_runtime.h>
#include <stdint.h>

// ---------- types ----------
typedef __attribute__((ext_vector_type(8))) short short8;
typedef __attribute__((ext_vector_type(4))) float floatx4;

__device__ inline float bf2f(unsigned short u) {
  union { unsigned int i; float f; } v; v.i = ((unsigned int)u) << 16; return v.f;
}
__device__ inline unsigned short f2bf(float f) {
  union { float f; unsigned int i; } v; v.f = f;
  unsigned int r = v.i + 0x7FFFu + ((v.i >> 16) & 1u);  // round-nearest-even
  return (unsigned short)(r >> 16);
}

// ---------- utility ----------
__global__ void zero_i32(int* __restrict__ p, int n) {
  int i = blockIdx.x * blockDim.x + threadIdx.x;
  if (i < n) p[i] = 0;
}

__global__ void cvt_bf16(const float* __restrict__ x, unsigned short* __restrict__ xb, int n) {
  int i = blockIdx.x * blockDim.x + threadIdx.x;
  if (i < n) xb[i] = f2bf(x[i]);
}

// count per (dst,rel): one int atomic per edge
__global__ void count_rel(const int* __restrict__ dst, const int* __restrict__ et,
                          int* __restrict__ cnt, int E) {
  int e = blockIdx.x * blockDim.x + threadIdx.x;
  if (e < E) atomicAdd(&cnt[(size_t)dst[e] * 8 + et[e]], 1);
}

// ---------- exclusive scan of cnt[n] -> eptr[n] (+eptr[n]=E), epos copy ----------
#define SCAN_T 256
#define SCAN_E 16   // 4096 elems per block

__global__ void scan1(const int* __restrict__ cnt, int* __restrict__ bsum, int n) {
  __shared__ int lds[SCAN_T];
  int base = blockIdx.x * (SCAN_T * SCAN_E);
  int tid = threadIdx.x;
  int s = 0;
#pragma unroll
  for (int j = 0; j < SCAN_E; ++j) {
    int i = base + tid * SCAN_E + j;
    if (i < n) s += cnt[i];
  }
  lds[tid] = s; __syncthreads();
  for (int off = SCAN_T / 2; off > 0; off >>= 1) {
    if (tid < off) lds[tid] += lds[tid + off];
    __syncthreads();
  }
  if (tid == 0) bsum[blockIdx.x] = lds[0];
}

__global__ void scan2(int* __restrict__ bsum, int* __restrict__ eptr, int nb, int n) {
  if (threadIdx.x == 0 && blockIdx.x == 0) {
    int run = 0;
    for (int b = 0; b < nb; ++b) { int v = bsum[b]; bsum[b] = run; run += v; }
    eptr[n] = run;
  }
}

__global__ void scan3(const int* __restrict__ cnt, const int* __restrict__ bsum,
                      int* __restrict__ eptr, int* __restrict__ epos, int n) {
  __shared__ int lds[SCAN_T];
  int base = blockIdx.x * (SCAN_T * SCAN_E);
  int tid = threadIdx.x;
  int loc[SCAN_E]; int s = 0;
#pragma unroll
  for (int j = 0; j < SCAN_E; ++j) {
    int i = base + tid * SCAN_E + j;
    loc[j] = (i < n) ? cnt[i] : 0; s += loc[j];
  }
  lds[tid] = s; __syncthreads();
  for (int off = 1; off < SCAN_T; off <<= 1) {   // Hillis-Steele inclusive
    int v = (tid >= off) ? lds[tid - off] : 0;
    __syncthreads();
    lds[tid] += v;
    __syncthreads();
  }
  int run = (tid > 0 ? lds[tid - 1] : 0) + bsum[blockIdx.x];
#pragma unroll
  for (int j = 0; j < SCAN_E; ++j) {
    int i = base + tid * SCAN_E + j;
    if (i < n) { eptr[i] = run; epos[i] = run; run += loc[j]; }
  }
}

// scatter edges into (dst,rel)-sorted order; entry = src
__global__ void scatter_edges(const int* __restrict__ src, const int* __restrict__ dst,
                              const int* __restrict__ et, int* __restrict__ epos,
                              int* __restrict__ entry, int E) {
  int e = blockIdx.x * blockDim.x + threadIdx.x;
  if (e < E) {
    int p = atomicAdd(&epos[(size_t)dst[e] * 8 + et[e]], 1);
    entry[p] = src[e];
  }
}

// ---------- pre-pack W (8 mats) + root into MFMA B-fragment layout, bf16 ----------
__global__ void prep_wb(const float* __restrict__ W, const float* __restrict__ root,
                        unsigned short* __restrict__ Wb) {
  int idx = blockIdx.x * blockDim.x + threadIdx.x;  // 9*4096
  if (idx >= 9 * 4096) return;
  int j = idx & 7, lane = (idx >> 3) & 63, nt = (idx >> 9) & 3, kc = (idx >> 11) & 1, mat = idx >> 12;
  int k = kc * 32 + (lane >> 4) * 8 + j, c = nt * 16 + (lane & 15);
  float v = (mat < 8) ? W[((size_t)mat * 64 + k) * 64 + c] : root[(size_t)k * 64 + c];
  Wb[idx] = f2bf(v);
}

// ---------- fused per-layer kernel: aggregate + transform, no intermediate in HBM.
// Block = 4 waves = one 16-dst tile. Stage 1: each wave aggregates 4 dsts over the
// merged edge range [eptr[d*8], eptr[d*8+8]) (unroll 8 -> 8 outstanding gathers),
// rel-id via boundary compares, means -> LDS (A-frag layout, stride 72 shorts).
// Stage 2: wave w = col-tile nt; 18 reg-resident B-frags; 18 MFMAs; direct output.
#define AROW 72
__global__ void __launch_bounds__(256, 3)
fused_layer(const unsigned short* __restrict__ xsrc, const int* __restrict__ eptr,
            const int* __restrict__ entry, const unsigned short* __restrict__ Wb,
            const float* __restrict__ bias, unsigned short* __restrict__ out_bf,
            float* __restrict__ out_f32, int N, int tiles, int relu_out)
{
  __shared__ unsigned short aLDS[9 * 16 * AROW];
  const int lane = threadIdx.x & 63;
  const int w    = threadIdx.x >> 6;     // wave id == output col-tile nt
  const int lc   = lane & 15;
  const int quad = lane >> 4;

  // B fragments for this wave's nt, held in VGPRs for the whole kernel
  short8 bfr[9][2];
#pragma unroll
  for (int mat = 0; mat < 9; ++mat)
#pragma unroll
    for (int kc = 0; kc < 2; ++kc)
      bfr[mat][kc] = *(const short8*)(Wb + (size_t)((mat * 2 + kc) * 4 + w) * 512 + lane * 8);
  const float bv = bias[w * 16 + lc];

  for (int t = blockIdx.x; t < tiles; t += gridDim.x) {
    const int nb = t << 4;
    __syncthreads();   // previous iteration's stage-2 LDS reads complete

    // ---- stage 1: aggregate 4 dsts per wave ----
    for (int i = 0; i < 4; ++i) {
      const int m = w * 4 + i;
      const int d = nb + m;
      int bnd[9];
#pragma unroll
      for (int j = 0; j < 9; ++j) bnd[j] = (d < N) ? eptr[(size_t)d * 8 + j] : 0;
      float s[8] = {0.f, 0.f, 0.f, 0.f, 0.f, 0.f, 0.f, 0.f};
      int e = bnd[0];
      const int end = bnd[8];
      for (; e + 8 <= end; e += 8) {
        int sr[8]; float v[8];
#pragma unroll
        for (int u = 0; u < 8; ++u) sr[u] = entry[e + u];
#pragma unroll
        for (int u = 0; u < 8; ++u) v[u] = bf2f(xsrc[(size_t)sr[u] * 64 + lane]);
#pragma unroll
        for (int u = 0; u < 8; ++u) {
          const int ee = e + u;
          const int r = (ee >= bnd[1]) + (ee >= bnd[2]) + (ee >= bnd[3]) + (ee >= bnd[4])
                      + (ee >= bnd[5]) + (ee >= bnd[6]) + (ee >= bnd[7]);
#pragma unroll
          for (int j = 0; j < 8; ++j) s[j] += (r == j) ? v[u] : 0.0f;
        }
      }
      for (; e < end; ++e) {
        const int sr0 = entry[e];
        const float v0 = bf2f(xsrc[(size_t)sr0 * 64 + lane]);
        const int r = (e >= bnd[1]) + (e >= bnd[2]) + (e >= bnd[3]) + (e >= bnd[4])
                    + (e >= bnd[5]) + (e >= bnd[6]) + (e >= bnd[7]);
#pragma unroll
        for (int j = 0; j < 8; ++j) s[j] += (r == j) ? v0 : 0.0f;
      }
#pragma unroll
      for (int j = 0; j < 8; ++j) {
        const float cnt = (float)(bnd[j + 1] - bnd[j]);
        const float mval = s[j] / fmaxf(cnt, 1.0f);
        aLDS[(j * 16 + m) * AROW + lane] = f2bf(mval);
      }
      aLDS[(8 * 16 + m) * AROW + lane] =
          (d < N) ? xsrc[(size_t)d * 64 + lane] : (unsigned short)0;
    }
    __syncthreads();

    // ---- stage 2: MFMA ----
    floatx4 dacc = {0.f, 0.f, 0.f, 0.f};
#pragma unroll
    for (int mat = 0; mat < 9; ++mat) {
      const short8 a0 = *(const short8*)&aLDS[(mat * 16 + lc) * AROW + quad * 8];
      const short8 a1 = *(const short8*)&aLDS[(mat * 16 + lc) * AROW + 32 + quad * 8];
      dacc = __builtin_amdgcn_mfma_f32_16x16x32_bf16(a0, bfr[mat][0], dacc, 0, 0, 0);
      dacc = __builtin_amdgcn_mfma_f32_16x16x32_bf16(a1, bfr[mat][1], dacc, 0, 0, 0);
    }
    const int c = w * 16 + lc;
#pragma unroll
    for (int i2 = 0; i2 < 4; ++i2) {
      const int r_ = nb + quad * 4 + i2;
      if (r_ < N) {
        const float vv = dacc[i2] + bv;
        if (relu_out) out_bf[(size_t)r_ * 64 + c] = f2bf(fmaxf(vv, 0.f));
        else          out_f32[(size_t)r_ * 64 + c] = vv;
      }
    }
  }
}

// graph segment boundaries from sorted batch
__global__ void glo_bounds(const int* __restrict__ batch, int* __restrict__ glo,
                           int N, int G) {
  int g = blockIdx.x * blockDim.x + threadIdx.x;
  if (g > G) return;
  if (g == G) { glo[G] = N; return; }
  int lo = 0, hi = N;
  while (lo < hi) { int mid = (lo + hi) >> 1; if (batch[mid] < g) lo = mid + 1; else hi = mid; }
  glo[g] = lo;
}

// fused mean-pool + finalize: one block per graph, contiguous node segment
__global__ void __launch_bounds__(256)
pool(const float* __restrict__ acc, const int* __restrict__ glo,
     float* __restrict__ out, int G)
{
  const int g = blockIdx.x;
  const int lane = threadIdx.x & 63;
  const int w = threadIdx.x >> 6;
  const int lo = glo[g], hi = glo[g + 1];
  float s = 0.f;
  for (int n = lo + w; n < hi; n += 4) s += acc[(size_t)n * 64 + lane];
  __shared__ float red[4][64];
  red[w][lane] = s;
  __syncthreads();
  if (w == 0) {
    float t = red[0][lane] + red[1][lane] + red[2][lane] + red[3][lane];
    out[(size_t)g * 64 + lane] = t / fmaxf((float)(hi - lo), 1.0f);
  }
}

// ---------- launch ----------
extern "C" void kernel_launch(void* const* d_in, const int* in_sizes, int n_in,
                              void* d_out, int out_size, void* d_ws, size_t ws_size,
                              hipStream_t stream)
{
  const float* x     = (const float*)d_in[0];
  const int*   ei    = (const int*)d_in[1];
  const int*   etype = (const int*)d_in[2];
  const int*   batch = (const int*)d_in[3];
  const float* W1    = (const float*)d_in[4];
  const float* root1 = (const float*)d_in[5];
  const float* b1    = (const float*)d_in[6];
  const float* W2    = (const float*)d_in[7];
  const float* root2 = (const float*)d_in[8];
  const float* b2    = (const float*)d_in[9];

  const int N = in_sizes[0] / 64;
  const int E = in_sizes[1] / 2;
  const int G = out_size / 64;
  const int* srcp = ei;
  const int* dstp = ei + E;

  // workspace carve-up (256B aligned), ~60 MB total
  char* ws = (char*)d_ws;
  size_t off = 0;
  auto carve = [&](size_t bytes) -> void* {
    void* p = ws + off; off = (off + bytes + 255) & ~(size_t)255; return p;
  };
  unsigned short* xb    = (unsigned short*)carve((size_t)N * 64 * 2);
  unsigned short* hb    = (unsigned short*)carve((size_t)N * 64 * 2);
  float*          acc   = (float*)carve((size_t)N * 64 * 4);
  int*            cnt   = (int*)carve((size_t)N * 8 * 4);
  int*            eptr  = (int*)carve(((size_t)N * 8 + 1) * 4);
  int*            epos  = (int*)carve((size_t)N * 8 * 4);
  int*            entry = (int*)carve((size_t)E * 4);
  unsigned short* Wb1   = (unsigned short*)carve((size_t)9 * 4096 * 2);
  unsigned short* Wb2   = (unsigned short*)carve((size_t)9 * 4096 * 2);
  int*            bsum  = (int*)carve(1024 * 4);
  int*            glo   = (int*)carve((size_t)(G + 1) * 4);
  (void)ws_size; (void)n_in;

  const int nseg = N * 8;
  const int nb_scan = (nseg + SCAN_T * SCAN_E - 1) / (SCAN_T * SCAN_E);
  const int nh = N * 64;
  const int tiles = (N + 15) >> 4;

  // ---- CSR build by (dst,rel) ----
  zero_i32<<<(nseg + 255) / 256, 256, 0, stream>>>(cnt, nseg);
  count_rel<<<(E + 255) / 256, 256, 0, stream>>>(dstp, etype, cnt, E);
  scan1<<<nb_scan, SCAN_T, 0, stream>>>(cnt, bsum, nseg);
  scan2<<<1, 64, 0, stream>>>(bsum, eptr, nb_scan, nseg);
  scan3<<<nb_scan, SCAN_T, 0, stream>>>(cnt, bsum, eptr, epos, nseg);
  scatter_edges<<<(E + 255) / 256, 256, 0, stream>>>(srcp, dstp, etype, epos, entry, E);

  // ---- prep ----
  cvt_bf16<<<(nh + 255) / 256, 256, 0, stream>>>(x, xb, nh);
  prep_wb<<<(9 * 4096 + 255) / 256, 256, 0, stream>>>(W1, root1, Wb1);
  prep_wb<<<(9 * 4096 + 255) / 256, 256, 0, stream>>>(W2, root2, Wb2);
  glo_bounds<<<1, 128, 0, stream>>>(batch, glo, N, G);

  // ---- layer 1 (relu fused, bf16 out) ----
  fused_layer<<<1024, 256, 0, stream>>>(xb, eptr, entry, Wb1, b1, hb,
                                        (float*)nullptr, N, tiles, 1);
  // ---- layer 2 (f32 out for pool) ----
  fused_layer<<<1024, 256, 0, stream>>>(hb, eptr, entry, Wb2, b2,
                                        (unsigned short*)nullptr, acc, N, tiles, 0);

  // ---- global mean pool ----
  pool<<<G, 256, 0, stream>>>(acc, glo, (float*)d_out, G);
}